// Round 6
// baseline (159.110 us; speedup 1.0000x reference)
//
#include <hip/hip_runtime.h>

#define T_TOK 1024
#define H_DIM 1024
#define I_DIM 768
#define E_NUM 8

// prep: x convert (512) + out zero (512) + router (1)
#define A_X 512
#define A_Z 512

#define GEMM1_BLOCKS 1536    // 8 xcd * 12 pairs * 16 m-rounds
#define GEMM2_BLOCKS 1024    // 8 xcd * 8 pairs * 16 m-rounds

// ring slot: B fp32 32KB + A bf16 8KB; ring of 2 = 81920B (2 blocks/CU = 160KB)
#define SLOT 40960
#define A_OFF 32768

typedef __bf16 bf16x8 __attribute__((ext_vector_type(8)));
typedef float  f32x4  __attribute__((ext_vector_type(4)));

__device__ inline bf16x8 cvt8(float4 a, float4 b, float s) {
    bf16x8 o;
    o[0] = (__bf16)(a.x * s); o[1] = (__bf16)(a.y * s);
    o[2] = (__bf16)(a.z * s); o[3] = (__bf16)(a.w * s);
    o[4] = (__bf16)(b.x * s); o[5] = (__bf16)(b.y * s);
    o[6] = (__bf16)(b.z * s); o[7] = (__bf16)(b.w * s);
    return o;
}

// fused dequant: two f32x4 LDS fragments -> one bf16x8 MFMA operand
__device__ inline bf16x8 cvt8f(f32x4 a, f32x4 b, float s) {
    bf16x8 o;
    o[0] = (__bf16)(a[0] * s); o[1] = (__bf16)(a[1] * s);
    o[2] = (__bf16)(a[2] * s); o[3] = (__bf16)(a[3] * s);
    o[4] = (__bf16)(b[0] * s); o[5] = (__bf16)(b[1] * s);
    o[6] = (__bf16)(b[2] * s); o[7] = (__bf16)(b[3] * s);
    return o;
}

// async 16B global -> LDS (linear dest: wave-uniform base + lane*16)
__device__ inline void async16(const void* g, void* l) {
    __builtin_amdgcn_global_load_lds(
        (const __attribute__((address_space(1))) unsigned int*)g,
        (__attribute__((address_space(3))) unsigned int*)l, 16, 0, 0);
}

#define VM_WAIT10 asm volatile("s_waitcnt vmcnt(10)" ::: "memory")
#define VM_WAIT0  asm volatile("s_waitcnt vmcnt(0)"  ::: "memory")

// ---- prep: x -> bf16, zero out, router -----------------------------------
__global__ __launch_bounds__(256) void prep_kernel(
    const float* __restrict__ x,   float4* __restrict__ out4,
    __bf16* __restrict__ xbf,
    const float* __restrict__ logits,
    int* __restrict__ counts, int* __restrict__ base,
    int* __restrict__ tok_list, float* __restrict__ wt_list)
{
    const int bx = blockIdx.x;
    if (bx < A_X) {
        int g = bx * 256 + threadIdx.x;   // < 131072
        const float4* src = (const float4*)x + (size_t)g * 2;
        *(bf16x8*)(xbf + (size_t)g * 8) = cvt8(src[0], src[1], 1.0f);
        return;
    }
    if (bx < A_X + A_Z) {
        int go = (bx - A_X) * 256 + threadIdx.x;  // < 131072, 32B each
        float4 z = make_float4(0.f, 0.f, 0.f, 0.f);
        out4[2 * go] = z; out4[2 * go + 1] = z;
        return;
    }
    // ---- router (single block) ----
    __shared__ int cnt[E_NUM];
    const int t0 = threadIdx.x;
    if (t0 < E_NUM) cnt[t0] = 0;
    __syncthreads();
#pragma unroll
    for (int tt = 0; tt < 4; tt++) {
        int t = t0 + tt * 256;
        float l[E_NUM];
#pragma unroll
        for (int e = 0; e < E_NUM; e++) l[e] = logits[t * E_NUM + e];
        int e0 = 0; float m0 = l[0];
#pragma unroll
        for (int e = 1; e < E_NUM; e++) if (l[e] > m0) { m0 = l[e]; e0 = e; }
        int e1 = -1; float m1 = -3e38f;
#pragma unroll
        for (int e = 0; e < E_NUM; e++) if (e != e0 && l[e] > m1) { m1 = l[e]; e1 = e; }
        float w0 = 1.0f / (1.0f + expf(m1 - m0));
        float w1 = 1.0f - w0;
        int p0 = atomicAdd(&cnt[e0], 1);
        tok_list[e0 * T_TOK + p0] = t;
        wt_list[e0 * T_TOK + p0] = w0;
        int p1 = atomicAdd(&cnt[e1], 1);
        tok_list[e1 * T_TOK + p1] = t;
        wt_list[e1 * T_TOK + p1] = w1;
    }
    __syncthreads();
    if (t0 == 0) {
        int s = 0;
        for (int e = 0; e < E_NUM; e++) { base[e] = s; counts[e] = cnt[e]; s += cnt[e]; }
    }
}

#define MFMA(A, B, C) __builtin_amdgcn_mfma_f32_16x16x32_bf16(A, B, C, 0, 0, 0)

// ---- GEMM1: gate_up = x_g @ dequant(w13)^T, + SiLU -----------------------
// M=64 x N=128(64 gate + 64 up), BK=64, K=16 steps. B staged as RAW FP32 via
// global_load_lds into a 2-slot ring; dequant (scale*cvt) happens on the
// LDS->reg read feeding MFMA. Counted vmcnt(10), raw s_barrier, no drain.
__global__ __launch_bounds__(256, 2) void gemm1_kernel(
    const __bf16* __restrict__ xbf,
    const float* __restrict__ w13,
    const float* __restrict__ w13s,
    const int* __restrict__ counts,
    const int* __restrict__ base,
    const int* __restrict__ tok_list,
    __bf16* __restrict__ act)
{
    const int bx = blockIdx.x;
    const int xcd = bx & 7, t = bx >> 3;
    const int p = t % 12, m = t / 12;      // 12 pairs per XCD, 16 m rounds
    const int P = xcd + 8 * p;             // pair id in [0,96)
    const int nb = P % 12, e = P / 12;
    const int count = counts[e];
    const int m0 = m * 64;
    if (m0 >= count) return;
    const int n0 = nb * 64;
    const int abase = base[e];

    __shared__ union { uint4 r4[2 * SLOT / 16]; float gu[64 * 132]; } u;  // 81920 B
    char* ring = (char*)u.r4;

    const int tid = threadIdx.x;
    const int wv = tid >> 6, ln = tid & 63;

    // ---- staging pointers (per lane; source pre-swizzled, LDS dest linear)
    // B region: rows 256B (64 fp32); chunk j (1KB) = rows wv*32+j*4+[0,4).
    // LDS slot s holds source granule s ^ (row & 7).
    const int rE = wv * 32 + (ln >> 4);          // rows for even j
    const int rO = rE + 4;                       // rows for odd j
    const int gE = (ln & 15) ^ (rE & 7);
    const int gO = (ln & 15) ^ (rO & 7);
    auto nbmap = [&](int r) { return (r < 64) ? (n0 + r) : (I_DIM + n0 + r - 64); };
    const char* pB0 = (const char*)w13 + ((size_t)e * 2 * I_DIM + nbmap(rE)) * 4096 + gE * 16;
    const char* pB1 = (const char*)w13 + ((size_t)e * 2 * I_DIM + nbmap(rO)) * 4096 + gO * 16;
    // A region: bf16 rows 128B; chunk jj (1KB) = rows wv*16+jj*8+[0,8).
    const int rA0 = wv * 16 + (ln >> 3), rA1 = rA0 + 8;
    const int tk0 = tok_list[e * T_TOK + ((m0 + rA0 < count) ? m0 + rA0 : 0)];
    const int tk1 = tok_list[e * T_TOK + ((m0 + rA1 < count) ? m0 + rA1 : 0)];
    const char* pA0 = (const char*)xbf + (size_t)tk0 * 2048 + (((ln & 7) ^ (rA0 & 7)) << 4);
    const char* pA1 = (const char*)xbf + (size_t)tk1 * 2048 + (((ln & 7) ^ (rA1 & 7)) << 4);

    // ---- per-lane dequant scales: B rows wid*32+lrow and +16, 8 k-blocks
    const int lane = ln, lrow = lane & 15, quad = lane >> 4, wid = wv;
    const int rB0 = wid * 32 + lrow, rB1 = rB0 + 16;
    const size_t sB0 = ((size_t)e * 2 * I_DIM + nbmap(rB0)) * 8;
    const size_t sB1 = ((size_t)e * 2 * I_DIM + nbmap(rB1)) * 8;
    float scl0[8], scl1[8];
#pragma unroll
    for (int kb = 0; kb < 8; kb++) { scl0[kb] = w13s[sB0 + kb]; scl1[kb] = w13s[sB1 + kb]; }

    // ---- compute-side LDS offsets
    const int bro0 = rB0 * 256, bro1 = rB1 * 256;
    const int glo = (((quad * 2) ^ (lrow & 7)) << 4);
    const int ghi = ((((quad * 2) | 1) ^ (lrow & 7)) << 4);
    int aoff[2][4];
#pragma unroll
    for (int kk = 0; kk < 2; kk++)
#pragma unroll
        for (int i = 0; i < 4; i++)
            aoff[kk][i] = (i * 16 + lrow) * 128 + (((kk * 4 + quad) ^ (lrow & 7)) << 4);

    f32x4 acc[4][2];
#pragma unroll
    for (int i = 0; i < 4; i++)
#pragma unroll
        for (int j = 0; j < 2; j++) { f32x4 z = {0.f, 0.f, 0.f, 0.f}; acc[i][j] = z; }

#define ISSUE(kc, sb) do { \
        async16(pB0 + (kc) * 256,          (sb) + wv * 8192); \
        async16(pB1 + (kc) * 256,          (sb) + wv * 8192 + 1024); \
        async16(pB0 + 32768 + (kc) * 256,  (sb) + wv * 8192 + 2048); \
        async16(pB1 + 32768 + (kc) * 256,  (sb) + wv * 8192 + 3072); \
        async16(pB0 + 65536 + (kc) * 256,  (sb) + wv * 8192 + 4096); \
        async16(pB1 + 65536 + (kc) * 256,  (sb) + wv * 8192 + 5120); \
        async16(pB0 + 98304 + (kc) * 256,  (sb) + wv * 8192 + 6144); \
        async16(pB1 + 98304 + (kc) * 256,  (sb) + wv * 8192 + 7168); \
        async16(pA0 + (kc) * 128,          (sb) + A_OFF + wv * 2048); \
        async16(pA1 + (kc) * 128,          (sb) + A_OFF + wv * 2048 + 1024); } while (0)

    auto compute = [&](const char* sb, float s0, float s1) {
        const char* Bb = sb;
        const char* Ab = sb + A_OFF;
#pragma unroll
        for (int kk = 0; kk < 2; kk++) {
            f32x4 l0 = *(const f32x4*)(Bb + bro0 + kk * 128 + glo);
            f32x4 h0 = *(const f32x4*)(Bb + bro0 + kk * 128 + ghi);
            f32x4 l1 = *(const f32x4*)(Bb + bro1 + kk * 128 + glo);
            f32x4 h1 = *(const f32x4*)(Bb + bro1 + kk * 128 + ghi);
            bf16x8 b0 = cvt8f(l0, h0, s0);
            bf16x8 b1 = cvt8f(l1, h1, s1);
#pragma unroll
            for (int i = 0; i < 4; i++) {
                bf16x8 a = *(const bf16x8*)(Ab + aoff[kk][i]);
                acc[i][0] = MFMA(a, b0, acc[i][0]);
                acc[i][1] = MFMA(a, b1, acc[i][1]);
            }
        }
    };

    VM_WAIT0;   // drain setup loads so counted vmcnt below is exact
    ISSUE(0, ring);
    ISSUE(1, ring + SLOT);
#pragma unroll
    for (int k = 0; k < 16; k++) {
        if (k < 15) { VM_WAIT10; } else { VM_WAIT0; }
        __builtin_amdgcn_s_barrier();
        compute(ring + (k & 1) * SLOT, scl0[k >> 1], scl1[k >> 1]);
        __builtin_amdgcn_s_barrier();
        if (k + 2 < 16) ISSUE(k + 2, ring + (k & 1) * SLOT);
    }
#undef ISSUE

    // epilogue: ring dead; reuse as gu
#pragma unroll
    for (int i = 0; i < 4; i++)
#pragma unroll
        for (int j = 0; j < 2; j++)
#pragma unroll
            for (int r = 0; r < 4; r++) {
                int mr = i * 16 + quad * 4 + r;
                int c = wid * 32 + j * 16 + lrow;
                u.gu[mr * 132 + c] = acc[i][j][r];
            }
    __syncthreads();

#pragma unroll
    for (int ii = 0; ii < 16; ii++) {
        int o = ii * 256 + tid;
        int mr = o >> 6, c = o & 63;
        if (m0 + mr < count) {
            float g  = u.gu[mr * 132 + c];
            float up = u.gu[mr * 132 + 64 + c];
            float a  = g / (1.0f + expf(-g)) * up;
            act[(size_t)(abase + m0 + mr) * I_DIM + n0 + c] = (__bf16)a;
        }
    }
}

// ---- GEMM2: out += w * (act @ dequant(w2)^T) -----------------------------
// M=64 x N=128, BK=64, K=12 steps; same fused-dequant ring pipeline.
__global__ __launch_bounds__(256, 2) void gemm2_kernel(
    const __bf16* __restrict__ act,
    const float* __restrict__ w2,
    const float* __restrict__ w2s,
    const int* __restrict__ counts,
    const int* __restrict__ base,
    const int* __restrict__ tok_list,
    const float* __restrict__ wt_list,
    float* __restrict__ out)
{
    const int bx = blockIdx.x;
    const int xcd = bx & 7, t = bx >> 3;
    const int p = t & 7, m = t >> 3;       // 8 pairs per XCD, 16 m rounds
    const int P = xcd + 8 * p;             // pair id in [0,64)
    const int nb = P & 7, e = P >> 3;      // nb == xcd: n-slice pinned per XCD
    const int count = counts[e];
    const int m0 = m * 64;
    if (m0 >= count) return;
    const int n0 = nb * 128;
    const int abase = base[e];

    __shared__ uint4 r4[2 * SLOT / 16];    // 81920 B
    char* ring = (char*)r4;

    const int tid = threadIdx.x;
    const int wv = tid >> 6, ln = tid & 63;

    // B: w2 fp32, rows 3072B (768 fp32), tile rows n0 + [0,128)
    const int rE = wv * 32 + (ln >> 4);
    const int rO = rE + 4;
    const int gE = (ln & 15) ^ (rE & 7);
    const int gO = (ln & 15) ^ (rO & 7);
    const char* pB0 = (const char*)w2 + ((size_t)e * H_DIM + n0 + rE) * 3072 + gE * 16;
    const char* pB1 = (const char*)w2 + ((size_t)e * H_DIM + n0 + rO) * 3072 + gO * 16;
    // A: act bf16, rows 1536B
    const int rA0 = wv * 16 + (ln >> 3), rA1 = rA0 + 8;
    int gr0 = abase + m0 + rA0; if (gr0 > 2 * T_TOK - 1) gr0 = 2 * T_TOK - 1;
    int gr1 = abase + m0 + rA1; if (gr1 > 2 * T_TOK - 1) gr1 = 2 * T_TOK - 1;
    const char* pA0 = (const char*)act + (size_t)gr0 * 1536 + (((ln & 7) ^ (rA0 & 7)) << 4);
    const char* pA1 = (const char*)act + (size_t)gr1 * 1536 + (((ln & 7) ^ (rA1 & 7)) << 4);

    const int lane = ln, lrow = lane & 15, quad = lane >> 4, wid = wv;
    const int rB0 = wid * 32 + lrow, rB1 = rB0 + 16;
    const size_t sB0 = ((size_t)e * H_DIM + n0 + rB0) * 6;
    const size_t sB1 = ((size_t)e * H_DIM + n0 + rB1) * 6;
    float scl0[6], scl1[6];
#pragma unroll
    for (int kb = 0; kb < 6; kb++) { scl0[kb] = w2s[sB0 + kb]; scl1[kb] = w2s[sB1 + kb]; }

    const int bro0 = rB0 * 256, bro1 = rB1 * 256;
    const int glo = (((quad * 2) ^ (lrow & 7)) << 4);
    const int ghi = ((((quad * 2) | 1) ^ (lrow & 7)) << 4);
    int aoff[2][4];
#pragma unroll
    for (int kk = 0; kk < 2; kk++)
#pragma unroll
        for (int i = 0; i < 4; i++)
            aoff[kk][i] = (i * 16 + lrow) * 128 + (((kk * 4 + quad) ^ (lrow & 7)) << 4);

    f32x4 acc[4][2];
#pragma unroll
    for (int i = 0; i < 4; i++)
#pragma unroll
        for (int j = 0; j < 2; j++) { f32x4 z = {0.f, 0.f, 0.f, 0.f}; acc[i][j] = z; }

#define ISSUE(kc, sb) do { \
        async16(pB0 + (kc) * 256,          (sb) + wv * 8192); \
        async16(pB1 + (kc) * 256,          (sb) + wv * 8192 + 1024); \
        async16(pB0 + 24576 + (kc) * 256,  (sb) + wv * 8192 + 2048); \
        async16(pB1 + 24576 + (kc) * 256,  (sb) + wv * 8192 + 3072); \
        async16(pB0 + 49152 + (kc) * 256,  (sb) + wv * 8192 + 4096); \
        async16(pB1 + 49152 + (kc) * 256,  (sb) + wv * 8192 + 5120); \
        async16(pB0 + 73728 + (kc) * 256,  (sb) + wv * 8192 + 6144); \
        async16(pB1 + 73728 + (kc) * 256,  (sb) + wv * 8192 + 7168); \
        async16(pA0 + (kc) * 128,          (sb) + A_OFF + wv * 2048); \
        async16(pA1 + (kc) * 128,          (sb) + A_OFF + wv * 2048 + 1024); } while (0)

    auto compute = [&](const char* sb, float s0, float s1) {
        const char* Bb = sb;
        const char* Ab = sb + A_OFF;
#pragma unroll
        for (int kk = 0; kk < 2; kk++) {
            f32x4 l0 = *(const f32x4*)(Bb + bro0 + kk * 128 + glo);
            f32x4 h0 = *(const f32x4*)(Bb + bro0 + kk * 128 + ghi);
            f32x4 l1 = *(const f32x4*)(Bb + bro1 + kk * 128 + glo);
            f32x4 h1 = *(const f32x4*)(Bb + bro1 + kk * 128 + ghi);
            bf16x8 b0 = cvt8f(l0, h0, s0);
            bf16x8 b1 = cvt8f(l1, h1, s1);
#pragma unroll
            for (int i = 0; i < 4; i++) {
                bf16x8 a = *(const bf16x8*)(Ab + aoff[kk][i]);
                acc[i][0] = MFMA(a, b0, acc[i][0]);
                acc[i][1] = MFMA(a, b1, acc[i][1]);
            }
        }
    };

    VM_WAIT0;   // drain setup loads
    ISSUE(0, ring);
    ISSUE(1, ring + SLOT);
#pragma unroll
    for (int k = 0; k < 12; k++) {
        if (k < 11) { VM_WAIT10; } else { VM_WAIT0; }
        __builtin_amdgcn_s_barrier();
        compute(ring + (k & 1) * SLOT, scl0[k >> 1], scl1[k >> 1]);
        __builtin_amdgcn_s_barrier();
        if (k + 2 < 12) ISSUE(k + 2, ring + (k & 1) * SLOT);
    }
#undef ISSUE

    // weighted atomic scatter
#pragma unroll
    for (int i = 0; i < 4; i++)
#pragma unroll
        for (int r = 0; r < 4; r++) {
            int mr = i * 16 + quad * 4 + r;
            if (m0 + mr < count) {
                int   tk = tok_list[e * T_TOK + m0 + mr];
                float w  = wt_list[e * T_TOK + m0 + mr];
#pragma unroll
                for (int j = 0; j < 2; j++) {
                    int h = n0 + wid * 32 + j * 16 + lrow;
                    atomicAdd(&out[(size_t)tk * H_DIM + h], w * acc[i][j][r]);
                }
            }
        }
}

extern "C" void kernel_launch(void* const* d_in, const int* in_sizes, int n_in,
                              void* d_out, int out_size, void* d_ws, size_t ws_size,
                              hipStream_t stream) {
    (void)in_sizes; (void)n_in; (void)out_size; (void)ws_size;
    const float* x      = (const float*)d_in[0];
    const float* logits = (const float*)d_in[1];
    const float* w13    = (const float*)d_in[2];
    const float* w13s   = (const float*)d_in[3];
    const float* w2     = (const float*)d_in[4];
    const float* w2s    = (const float*)d_in[5];
    float* out = (float*)d_out;

    char* ws = (char*)d_ws;
    int*    counts   = (int*)ws;                              // @0
    int*    base     = (int*)(ws + 128);                      // @128
    int*    tok_list = (int*)(ws + 256);                      // 32 KB
    float*  wt_list  = (float*)(ws + 256 + 32768);            // 32 KB
    __bf16* act      = (__bf16*)(ws + 65792);                 // 3 MB
    __bf16* xbf      = (__bf16*)(ws + 65792 + 3145728);       // 2 MB

    prep_kernel<<<dim3(A_X + A_Z + 1), 256, 0, stream>>>(
        x, (float4*)out, xbf, logits, counts, base, tok_list, wt_list);
    gemm1_kernel<<<dim3(GEMM1_BLOCKS), 256, 0, stream>>>(
        xbf, w13, w13s, counts, base, tok_list, act);
    gemm2_kernel<<<dim3(GEMM2_BLOCKS), 256, 0, stream>>>(
        act, w2, w2s, counts, base, tok_list, wt_list, out);
}